// Round 2
// baseline (247.856 us; speedup 1.0000x reference)
//
#include <hip/hip_runtime.h>
#include <hip/hip_bf16.h>
#include <math.h>

typedef __hip_bfloat16 bf16;

#define HD 96
#define WD 96
#define HW 9216            // 96*96
#define BATCH 4

// ws float-offset layout (fp32 param block, then bf16 x1 buffer)
#define OFF_WR    0        // 16x64  scaled w_reduce
#define OFF_CR    1024     // 16     reduce-BN additive
#define OFF_WSP   1040     // 196x16 w_span
#define OFF_BSP   4176     // 196    b_span
#define OFF_SI    4372     // 64     bn_i scale
#define OFF_CI    4436     // 64     bn_i additive
#define OFF_WT    4500     // 128x128 combined conv|map weight, c-major: WT[c*128+o]
#define OFF_BIAS  20884    // 128    combined bias
#define X1_BYTE_OFF 84064  // bf16 x1 buffer, BATCH*64*HW elems (4.72 MB)

__device__ __forceinline__ float geluf(float v) {
    return 0.5f * v * (1.0f + erff(v * 0.7071067811865475f));
}

// ---------------- K0: fold BN params into weights (1 block) ----------------
__global__ __launch_bounds__(256) void k_fold(
    const float* __restrict__ wred,
    const float* __restrict__ gr, const float* __restrict__ br,
    const float* __restrict__ mr, const float* __restrict__ vr,
    const float* __restrict__ wspan, const float* __restrict__ bspan,
    const float* __restrict__ gi, const float* __restrict__ bi,
    const float* __restrict__ mi, const float* __restrict__ vi,
    const float* __restrict__ wconv,
    const float* __restrict__ gc, const float* __restrict__ bc,
    const float* __restrict__ mc, const float* __restrict__ vc,
    const float* __restrict__ wmap, const float* __restrict__ bmap,
    const float* __restrict__ gm, const float* __restrict__ bm,
    const float* __restrict__ mmn, const float* __restrict__ vm,
    float* __restrict__ wsf)
{
    const int tid = threadIdx.x;
    for (int i = tid; i < 1024; i += 256) {
        int r = i >> 6;
        float sr = gr[r] * rsqrtf(vr[r] + 1e-5f);
        wsf[OFF_WR + i] = sr * wred[i];
    }
    if (tid < 16) {
        float sr = gr[tid] * rsqrtf(vr[tid] + 1e-5f);
        wsf[OFF_CR + tid] = br[tid] - mr[tid] * sr;
    }
    for (int i = tid; i < 3136; i += 256) wsf[OFF_WSP + i] = wspan[i];
    if (tid < 196) wsf[OFF_BSP + tid] = bspan[tid];
    if (tid < 64) {
        float si = gi[tid] * rsqrtf(vi[tid] + 1e-5f);
        wsf[OFF_SI + tid] = si;
        wsf[OFF_CI + tid] = bi[tid] - mi[tid] * si;
    }
    for (int i = tid; i < 16384; i += 256) {
        int c = i >> 7, o = i & 127;
        float v;
        if (c < 64) {
            float sc = gc[o] * rsqrtf(vc[o] + 1e-5f);
            v = sc * wconv[o * 64 + c];
        } else {
            float sm = gm[o] * rsqrtf(vm[o] + 1e-5f);
            v = sm * wmap[o * 64 + (c - 64)];
        }
        wsf[OFF_WT + i] = v;
    }
    if (tid < 128) {
        float sc = gc[tid] * rsqrtf(vc[tid] + 1e-5f);
        float sm = gm[tid] * rsqrtf(vm[tid] + 1e-5f);
        wsf[OFF_BIAS + tid] = (bc[tid] - mc[tid] * sc)
                            + sm * bmap[tid]
                            + (bm[tid] - mmn[tid] * sm);
    }
}

// ---------------- K1: involution + bn_i + GELU -> x1 (bf16 in ws) ----------
// Block: 256 threads = 64 pixels (8x8 tile) x 4 groups. Grid (12,12,4).
__global__ __launch_bounds__(256, 2) void k_inv(
    const float* __restrict__ x, const float* __restrict__ wsf,
    bf16* __restrict__ x1)
{
    __shared__ float xs[64 * 196];   // [c][14*14] halo tile
    __shared__ float ts[64 * 20];    // [pixel][16] t, stride 20

    const int tid = threadIdx.x;
    const int b  = blockIdx.z;
    const int ty = blockIdx.y * 8, tx = blockIdx.x * 8;

    const float* xb = x + (size_t)b * 64 * HW;
    for (int e = tid; e < 64 * 196; e += 256) {
        int c = e / 196, pos = e % 196;
        int py = pos / 14, px = pos % 14;
        int gy = ty + py - 3, gx = tx + px - 3;
        float v = 0.0f;
        if (gy >= 0 && gy < HD && gx >= 0 && gx < WD)
            v = xb[c * HW + gy * WD + gx];
        xs[e] = v;
    }
    __syncthreads();

    const int p = tid & 63;
    const int q = __builtin_amdgcn_readfirstlane(tid >> 6);  // wave-uniform
    const int py0 = p >> 3, px0 = p & 7;
    const int center = (py0 + 3) * 14 + (px0 + 3);

    // t[q*4 .. q*4+3] for this pixel (weights: wave-uniform scalar loads)
    float t4[4];
    #pragma unroll
    for (int r = 0; r < 4; ++r) t4[r] = wsf[OFF_CR + q * 4 + r];
    for (int c = 0; c < 64; ++c) {
        float xc = xs[c * 196 + center];
        #pragma unroll
        for (int r = 0; r < 4; ++r) t4[r] += wsf[OFF_WR + (q * 4 + r) * 64 + c] * xc;
    }
    #pragma unroll
    for (int r = 0; r < 4; ++r) ts[p * 20 + q * 4 + r] = fmaxf(t4[r], 0.0f);
    __syncthreads();

    float tr[16];
    #pragma unroll
    for (int r = 0; r < 16; ++r) tr[r] = ts[p * 20 + r];

    const int g = q;
    float inv[16];
    #pragma unroll
    for (int i = 0; i < 16; ++i) inv[i] = 0.0f;

    for (int kk = 0; kk < 49; ++kk) {
        const int row = g * 49 + kk;
        float kv = wsf[OFF_BSP + row];
        #pragma unroll
        for (int r = 0; r < 16; ++r) kv += wsf[OFF_WSP + row * 16 + r] * tr[r];
        const int nb = (py0 + kk / 7) * 14 + (px0 + kk % 7);
        #pragma unroll
        for (int c16 = 0; c16 < 16; ++c16)
            inv[c16] += kv * xs[(g * 16 + c16) * 196 + nb];
    }

    bf16* x1b = x1 + (size_t)b * 64 * HW + (ty + py0) * WD + (tx + px0);
    #pragma unroll
    for (int c16 = 0; c16 < 16; ++c16) {
        int c = g * 16 + c16;
        float v = inv[c16] * wsf[OFF_SI + c] + wsf[OFF_CI + c];
        x1b[c * HW] = __float2bfloat16(geluf(v));
    }
}

// ---------------- K2: 128x128 pointwise GEMM + GELU -> out -----------------
// Block: 256 threads = 64 pixels x 4 output-quarters. Grid 576.
__global__ __launch_bounds__(256) void k_out(
    const float* __restrict__ x, const bf16* __restrict__ x1,
    const float* __restrict__ wsf, float* __restrict__ out)
{
    const int tid  = threadIdx.x;
    const int lane = tid & 63;
    const int q    = __builtin_amdgcn_readfirstlane(tid >> 6);  // wave-uniform
    const int pix  = blockIdx.x * 64 + lane;
    const int b = pix / HW, hw = pix % HW;

    const bf16*  x1b = x1 + (size_t)b * 64 * HW + hw;
    const float* xb  = x  + (size_t)b * 64 * HW + hw;
    const float* WT  = wsf + OFF_WT + q * 32;

    float acc[32];
    #pragma unroll
    for (int o = 0; o < 32; ++o) acc[o] = wsf[OFF_BIAS + q * 32 + o];

    for (int c = 0; c < 64; ++c) {
        float zc = __bfloat162float(x1b[c * HW]);
        const float* w = WT + c * 128;
        #pragma unroll
        for (int o = 0; o < 32; ++o) acc[o] += w[o] * zc;
    }
    for (int c = 0; c < 64; ++c) {
        float zc = xb[c * HW];
        const float* w = WT + (64 + c) * 128;
        #pragma unroll
        for (int o = 0; o < 32; ++o) acc[o] += w[o] * zc;
    }

    float* ob = out + (size_t)b * 128 * HW + hw;
    #pragma unroll
    for (int o = 0; o < 32; ++o)
        ob[(o + q * 32) * HW] = geluf(acc[o]);
}

// ---------------------------------------------------------------------------
extern "C" void kernel_launch(void* const* d_in, const int* in_sizes, int n_in,
                              void* d_out, int out_size, void* d_ws, size_t ws_size,
                              hipStream_t stream)
{
    const float* x     = (const float*)d_in[0];
    const float* wred  = (const float*)d_in[1];
    const float* gr    = (const float*)d_in[2];
    const float* br    = (const float*)d_in[3];
    const float* mr    = (const float*)d_in[4];
    const float* vr    = (const float*)d_in[5];
    const float* wspan = (const float*)d_in[6];
    const float* bspan = (const float*)d_in[7];
    const float* gi    = (const float*)d_in[8];
    const float* bi    = (const float*)d_in[9];
    const float* mi    = (const float*)d_in[10];
    const float* vi    = (const float*)d_in[11];
    const float* wconv = (const float*)d_in[12];
    const float* gc    = (const float*)d_in[13];
    const float* bc    = (const float*)d_in[14];
    const float* mc    = (const float*)d_in[15];
    const float* vc    = (const float*)d_in[16];
    const float* wmap  = (const float*)d_in[17];
    const float* bmap  = (const float*)d_in[18];
    const float* gm    = (const float*)d_in[19];
    const float* bm    = (const float*)d_in[20];
    const float* mmn   = (const float*)d_in[21];
    const float* vm    = (const float*)d_in[22];

    float* wsf = (float*)d_ws;
    bf16*  x1  = (bf16*)((char*)d_ws + X1_BYTE_OFF);
    float* out = (float*)d_out;

    hipLaunchKernelGGL(k_fold, dim3(1), dim3(256), 0, stream,
                       wred, gr, br, mr, vr, wspan, bspan, gi, bi, mi, vi,
                       wconv, gc, bc, mc, vc, wmap, bmap, gm, bm, mmn, vm, wsf);
    hipLaunchKernelGGL(k_inv, dim3(12, 12, BATCH), dim3(256), 0, stream, x, wsf, x1);
    hipLaunchKernelGGL(k_out, dim3((BATCH * HW) / 64), dim3(256), 0, stream, x, x1, wsf, out);
}